// Round 13
// baseline (92.888 us; speedup 1.0000x reference)
//
#include <hip/hip_runtime.h>
#include <stdint.h>

// Problem constants
#define CIN_  16
#define KS_   13
#define AS_   12
#define R_    12
#define KT    96            // kappa per step
#define NSTEP 26
#define LDP   104           // X LDS pitch (96 + 8 pad)

typedef float  f32x4  __attribute__((ext_vector_type(4)));
typedef __bf16 bf16x4 __attribute__((ext_vector_type(4)));
typedef __bf16 bf16x8 __attribute__((ext_vector_type(8)));

// ---------------------------------------------------------------------------
// Kernel 1: expand W into per-wave-grouped MFMA-fragment order (as R11).
// fid = kt*36 + w*9 + (mtl*3 + ks), global mt = w*3 + mtl (1 KB frags).
// Lane l, elem e: A[row = mt*16 + (l&15)][kappa = kt*96 + ks*32 + (l>>4)*8 + e]
// row=(d*12+r), kappa=(c*13+k)*12+a,
//   Wfull[d,c,r,k,a] = W[d,c, idx_map[ tivr[r,k]*12 + tir[r,a] ]].
// ---------------------------------------------------------------------------
__global__ void build_wmatf(const float* __restrict__ W,
                            const int* __restrict__ idx_map,
                            const int* __restrict__ tivr,   // [12][13]
                            const int* __restrict__ tir,    // [12][12]
                            __bf16* __restrict__ WmatF) {
  int gid  = blockIdx.x * blockDim.x + threadIdx.x;   // 0..59903 (= 936*64)
  int lane = gid & 63;
  int fid  = gid >> 6;              // 0..935
  int kt   = fid / 36;
  int rem  = fid - kt * 36;
  int w    = rem / 9;
  int sub  = rem - w * 9;
  int mtl  = sub / 3;
  int ks   = sub - mtl * 3;
  int mt   = w * 3 + mtl;

  int row = mt * 16 + (lane & 15);
  int d = row / R_;
  int r = row - d * R_;

  bf16x8 v;
#pragma unroll
  for (int e = 0; e < 8; ++e) {
    int kap = kt * KT + ks * 32 + (lane >> 4) * 8 + e;
    int c = kap / (KS_ * AS_);
    int t = kap - c * (KS_ * AS_);
    int k = t / AS_;
    int a = t - k * AS_;
    int s = idx_map[tivr[r * KS_ + k] * AS_ + tir[r * AS_ + a]];
    v[e] = (__bf16)W[(d * CIN_ + c) * 36 + s];
  }
  *(bf16x8*)(WmatF + (size_t)gid * 8) = v;
}

// ---------------------------------------------------------------------------
// Kernel 2: out(b,d,p,r) = Wmat(192 x 2496) @ X(2496 x [b,p])
// 1024 WGs x 256 threads, BN=32 -> FOUR independent barrier domains per CU
// (R11 post-mortem: 2 domains phase-lock at ~60% HBM duty; components sum).
// VGPR<=128 (launch_bounds(256,4)), LDS 13.3 KB/WG. Wave: 48 rows x 32 cols.
// A in registers, single-buffered, reloaded per step from L2-hot WmatF at
// phase END (so its vmcnt wait never drains the newer x prefetch).
// X through LDS bf16 (6 KB/step), double-buffered. One lgkmcnt(0)+s_barrier
// per step; all loads unconditional.
// ---------------------------------------------------------------------------
__global__ __launch_bounds__(256, 4)
void s2conv(const float* __restrict__ x,
            const __bf16* __restrict__ WmatF,
            float* __restrict__ out) {
  __shared__ __bf16 Xs[2][32][LDP];   // 2 x 6.6 KB = 13.3 KB

  const int tid  = threadIdx.x;
  const int lane = tid & 63;
  const int wave = tid >> 6;        // 0..3: owns rows wave*48..wave*48+47
  const int l15  = lane & 15;
  const int l4   = lane >> 4;

  const int wg = blockIdx.x;        // 0..1023
  const int b  = wg >> 7;           // 0..7
  const int p0 = (wg & 127) << 5;   // 32-col tile

  // x staging map (thread-fixed): g = j*256 + tid in [0,768): ck = g/96,
  // r = g%96 -> pl = r/3, a = (r%3)*4. Contiguous 1.5 KB span per ck.
  int xck[3], xr[3], xpl[3], xa[3];
#pragma unroll
  for (int j = 0; j < 3; ++j) {
    int g = j * 256 + tid;
    xck[j] = g / 96;
    xr[j]  = g - xck[j] * 96;
    xpl[j] = xr[j] / 3;
    xa[j]  = (xr[j] - xpl[j] * 3) * 4;
  }
  const char* xb = (const char*)x +
      ((size_t)b * 208 * 49152 + (size_t)p0 * 12) * 4;

  f32x4 acc[3][2];
#pragma unroll
  for (int i = 0; i < 3; ++i)
#pragma unroll
    for (int j = 0; j < 2; ++j)
      acc[i][j] = f32x4{0.f, 0.f, 0.f, 0.f};

  // ---- A: 9 frags from L2 (contiguous 9 KB per (kt,wave)) ------------------
  const char* aBase = (const char*)WmatF + (size_t)wave * 9216 + lane * 16;
  bf16x8 aA[9];
  auto loadA = [&](int kt) {
    const char* gk = aBase + (size_t)kt * 36864;
#pragma unroll
    for (int f = 0; f < 9; ++f)
      aA[f] = *(const bf16x8*)(gk + f * 1024);
  };

  auto load_x = [&](int kt, f32x4 (&st)[3]) {
#pragma unroll
    for (int j = 0; j < 3; ++j)
      st[j] = *(const f32x4*)(xb + (size_t)(kt * 8 + xck[j]) * 196608
                                  + xr[j] * 16);
  };

  auto write_X = [&](int buf, f32x4 (&st)[3]) {
    char* xsb = (char*)&Xs[buf][0][0];
#pragma unroll
    for (int j = 0; j < 3; ++j) {
      bf16x4 v = __builtin_convertvector(st[j], bf16x4);
      *(bf16x4*)(xsb + (xpl[j] * LDP + xck[j] * 12 + xa[j]) * 2) = v;
    }
  };

  auto mfma_phase = [&](int buf) {
    const __bf16* xsb = &Xs[buf][0][0];
#pragma unroll
    for (int ks = 0; ks < 3; ++ks) {
      bf16x8 bfr[2];
#pragma unroll
      for (int nt = 0; nt < 2; ++nt)
        bfr[nt] = *(const bf16x8*)(xsb + (nt * 16 + l15) * LDP
                                       + ks * 32 + l4 * 8);
#pragma unroll
      for (int mtl = 0; mtl < 3; ++mtl)
#pragma unroll
        for (int nt = 0; nt < 2; ++nt)
          acc[mtl][nt] = __builtin_amdgcn_mfma_f32_16x16x32_bf16(
              aA[mtl * 3 + ks], bfr[nt], acc[mtl][nt], 0, 0, 0);
    }
  };

  auto barrier = [&]() {
    asm volatile("s_waitcnt lgkmcnt(0)" ::: "memory");  // ds_writes visible
    __builtin_amdgcn_s_barrier();                        // no vmcnt drain
  };

  // ---- prologue ------------------------------------------------------------
  f32x4 s0[3], s1[3];
  load_x(0, s0);
  loadA(0);
  load_x(1, s1);
  __builtin_amdgcn_sched_barrier(0);
  write_X(0, s0);
  barrier();

  // ---- main loop: steps 0..23; A(t+1) issued AFTER mfma(t) (newest) so its
  //      vmcnt wait at step t+1 leaves x(t+2)/x(t+3) in flight.
#pragma unroll 1
  for (int t = 0; t < 24; t += 2) {
    // even step t (buf 0)
    load_x(t + 2, s0);
    __builtin_amdgcn_sched_barrier(0);
    write_X(1, s1);
    mfma_phase(0);
    loadA(t + 1);
    barrier();

    // odd step t+1 (buf 1)
    load_x(t + 3, s1);
    __builtin_amdgcn_sched_barrier(0);
    write_X(0, s0);
    mfma_phase(1);
    loadA(t + 2);
    barrier();
  }

  // ---- tail: step 24 (buf 0), step 25 (buf 1); no x loads ------------------
  write_X(1, s1);                      // X(25) (x loaded at step 23)
  mfma_phase(0);                       // X(24)
  loadA(25);
  barrier();
  mfma_phase(1);                       // X(25)

  // ---- epilogue: rows wave*48 + mtl*16 + l4*4, col p0 + nt*16 + l15 --------
#pragma unroll
  for (int mtl = 0; mtl < 3; ++mtl) {
    int mrow0 = wave * 48 + mtl * 16 + l4 * 4;   // r0 in {0,4,8} -> same d
    int d  = mrow0 / 12;
    int r0 = mrow0 - d * 12;
#pragma unroll
    for (int nt = 0; nt < 2; ++nt) {
      int p = p0 + nt * 16 + l15;
      float* dst = out + (size_t)((b * 16 + d) * 4096 + p) * 12 + r0;
      *(f32x4*)dst = acc[mtl][nt];               // 16B aligned
    }
  }
}

// ---------------------------------------------------------------------------
extern "C" void kernel_launch(void* const* d_in, const int* in_sizes, int n_in,
                              void* d_out, int out_size, void* d_ws, size_t ws_size,
                              hipStream_t stream) {
  const float* x       = (const float*)d_in[0];  // (8,16,13,4096,12) f32
  const float* W       = (const float*)d_in[1];  // (16,16,36) f32
  const int*   idx_map = (const int*)d_in[2];    // (156,)
  const int*   tivr    = (const int*)d_in[3];    // (12,13)
  const int*   tir     = (const int*)d_in[4];    // (12,12)
  float*       out     = (float*)d_out;          // (8,16,4096,12) f32
  __bf16*      WmatF   = (__bf16*)d_ws;          // 936 KB, fragment-ordered

  build_wmatf<<<dim3(117), dim3(512), 0, stream>>>(W, idx_map, tivr, tir, WmatF);
  s2conv<<<dim3(1024), dim3(256), 0, stream>>>(x, WmatF, out);
}